// Round 11
// baseline (169.054 us; speedup 1.0000x reference)
//
#include <hip/hip_runtime.h>
#include <hip/hip_bf16.h>
#include <stdint.h>
#include <stddef.h>

// Problem constants (B=2, L=2048, D=32, H=8)
#define LL 2048

typedef __attribute__((ext_vector_type(8))) short short8;
typedef __attribute__((ext_vector_type(4))) float f32x4;
typedef unsigned short ushort_t;
typedef unsigned int uint_t;

// ws layout (float elements). Total ~17.9 MB.
#define VAOFF   1048576u   // V_agg f32 [bh][l][d]
#define QS16OFF 2097152u   // Q*scale*log2e bf16 [bh][l][d]
#define KS16OFF 2621440u   // K*grade_signs bf16 [bh][l][d]
#define KG16OFF 3145728u   // K raw bf16 [bh][l][d]
#define VT16OFF 3670016u   // V^T bf16 [bh*32+d][l] (key-permuted)
#define RVOFF   4194304u   // row_valid f32, B*L
#define MBOFF   4198400u   // packed mask bits [b][qsb][ks][kt][l15][rr]
#define C2TOFF  4460544u   // cayley^T bf16 [k][ij], 32768 elems

__device__ __forceinline__ ushort_t f2bf(float f) {
    unsigned int u = __float_as_uint(f);
    u += 0x7FFFu + ((u >> 16) & 1u);   // RNE
    return (ushort_t)(u >> 16);
}
__device__ __forceinline__ float bf2f(ushort_t s) {
    return __uint_as_float(((unsigned int)s) << 16);
}
__device__ __forceinline__ uint_t pkbf(float a, float b) {   // RNE pack (one-time)
    __hip_bfloat162 h = __float22bfloat162_rn(float2{a, b});
    return *(uint_t*)&h;
}
// cheap add-half-rounded bf16 pair pack (hot loops)
__device__ __forceinline__ uint_t pk2(float a, float b) {
    const uint_t ua = (__float_as_uint(a) + 0x8000u) >> 16;
    const uint_t ub = (__float_as_uint(b) + 0x8000u) & 0xFFFF0000u;
    return ua | ub;
}

// ---------------------------------------------------------------------------
// Fused prep: [0,1024) mask detect+bit-pack -- NEW index layout
// [b][qsb 32][ks 4][kt 16][l15 16][rr 4] so attn lane (l15) reads its four
// row-halves' words as ONE dwordx4; [1024,1536) QKV 8 pos/block + direct
// permuted-V^T; [1536,1540) cayley^T bf16. Disjoint writes.
// ---------------------------------------------------------------------------
__global__ __launch_bounds__(256) void prep_kernel(
        const uint_t* __restrict__ mraw, uint_t* __restrict__ mb,
        const float* __restrict__ x,
        const float* __restrict__ Wq, const float* __restrict__ Wk,
        const float* __restrict__ Wv, const float* __restrict__ gs,
        const float* __restrict__ cayley, float* __restrict__ ws) {
    __shared__ float smem[8192];
    const int t = threadIdx.x;

    if (blockIdx.x < 1024) {
        int* sI = (int*)smem;
        int* sF = ((int*)smem) + 1;
        if (t == 0) { *sI = 1; *sF = 1; }
        __syncthreads();
        const size_t blk = blockIdx.x;
        const uint4* p8 = (const uint4*)(mraw + blk * 2048 + t * 8);
        const uint4 a = p8[0], c = p8[1];
        const uint_t d8[8] = {a.x, a.y, a.z, a.w, c.x, c.y, c.z, c.w};
        int oi = 1, of = 1;
#pragma unroll
        for (int i = 0; i < 8; ++i) {
            if (d8[i] > 1u) oi = 0;
            if (d8[i] != 0u && d8[i] != 0x3F800000u) of = 0;
        }
        if (!oi) atomicAnd(sI, 0);
        if (!of) atomicAnd(sF, 0);
        __syncthreads();
        const int mtype = *sI ? 1 : (*sF ? 2 : 0);
        uint_t w = 0;
        if (mtype == 0) {
#pragma unroll
            for (int i = 0; i < 8; ++i) {
#pragma unroll
                for (int by = 0; by < 4; ++by)
                    w |= (((d8[i] >> (8 * by)) & 0xFFu) ? 1u : 0u) << (i * 4 + by);
            }
        } else {
            const uint4* pi = (const uint4*)(mraw + blk * 8192 + (size_t)t * 32);
#pragma unroll
            for (int i = 0; i < 8; ++i) {
                const uint4 d = pi[i];
                if (mtype == 1) {
                    w |= (d.x << (i * 4)) | (d.y << (i * 4 + 1)) |
                         (d.z << (i * 4 + 2)) | (d.w << (i * 4 + 3));
                } else {
                    w |= ((d.x ? 1u : 0u) << (i * 4)) | ((d.y ? 1u : 0u) << (i * 4 + 1)) |
                         ((d.z ? 1u : 0u) << (i * 4 + 2)) | ((d.w ? 1u : 0u) << (i * 4 + 3));
                }
            }
        }
        // word for (row, w0=key/32): row = W>>6, w0 = W&63; ks=w0&3, kt=w0>>2
        const uint_t W = (uint_t)(blk * 256 + t);
        const uint_t row = W >> 6, w0 = W & 63u;
        const uint_t bb = row >> 11, r11 = row & 2047u;
        const uint_t qsb = r11 >> 6, rr = (r11 >> 4) & 3u, lw = r11 & 15u;
        const uint_t idx = ((((bb * 32u + qsb) * 4u + (w0 & 3u)) * 16u + (w0 >> 2)) * 16u + lw) * 4u + rr;
        mb[idx] = w;
    } else if (blockIdx.x < 1536) {
        ushort_t* Qs16 = (ushort_t*)(ws + QS16OFF);
        ushort_t* Ks16 = (ushort_t*)(ws + KS16OFF);
        ushort_t* Kg16 = (ushort_t*)(ws + KG16OFF);
        ushort_t* Vt   = (ushort_t*)(ws + VT16OFF);
        float* sX = smem;
        const int pid0 = (blockIdx.x - 1024) * 8;
        if (t < 64) ((float4*)sX)[t] = ((const float4*)(x + (size_t)pid0 * 32))[t];
        float wq[32], wk[32], wv[32];
        const float4* wqp = (const float4*)(Wq + t * 32);
        const float4* wkp = (const float4*)(Wk + t * 32);
        const float4* wvp = (const float4*)(Wv + t * 32);
#pragma unroll
        for (int d4 = 0; d4 < 8; ++d4) {
            float4 a = wqp[d4]; wq[4*d4]=a.x; wq[4*d4+1]=a.y; wq[4*d4+2]=a.z; wq[4*d4+3]=a.w;
            float4 b = wkp[d4]; wk[4*d4]=b.x; wk[4*d4+1]=b.y; wk[4*d4+2]=b.z; wk[4*d4+3]=b.w;
            float4 c = wvp[d4]; wv[4*d4]=c.x; wv[4*d4+1]=c.y; wv[4*d4+2]=c.z; wv[4*d4+3]=c.w;
        }
        const float sgn = gs[t & 31];
        const float qscale = 0.17677669529663687f * 1.4426950408889634f;
        const int h = t >> 5, dd = t & 31;
        const int b0 = pid0 >> 11, l0 = pid0 & 2047;
        __syncthreads();
        ushort4 vt4[2];
        for (int r = 0; r < 8; ++r) {
            const int pid = pid0 + r;
            const int b = pid >> 11, l = pid & 2047;
            float q = 0.f, k = 0.f, v = 0.f;
#pragma unroll
            for (int d = 0; d < 32; ++d) {
                const float xv = sX[r * 32 + d];
                q += xv * wq[d]; k += xv * wk[d]; v += xv * wv[d];
            }
            const size_t o = ((size_t)((b * 8 + h) * 2048 + l)) * 32 + dd;
            Qs16[o] = f2bf(q * qscale);
            Ks16[o] = f2bf(k * sgn);
            Kg16[o] = f2bf(k);
            ((ushort_t*)&vt4[r >> 2])[r & 3] = f2bf(v);
        }
        ushort_t* vtrow = Vt + ((size_t)((b0 * 8 + h) * 32 + dd)) * 2048;
#pragma unroll
        for (int g4 = 0; g4 < 2; ++g4) {
            const int lg = l0 + g4 * 4;
            const int lloc = lg & 63;
            const int g = lloc >> 5, tt = (lloc >> 4) & 1, q4 = (lloc >> 2) & 3;
            const int pc = (lg & ~63) + g * 32 + q4 * 8 + tt * 4;
            *(ushort4*)(vtrow + pc) = vt4[g4];
        }
    } else {
        float* sC = smem;
        ushort_t* C2t = (ushort_t*)(ws + C2TOFF);
        const int ij0 = (blockIdx.x - 1536) * 256;   // ij in [0,1024)
#pragma unroll
        for (int i = 0; i < 8; ++i)
            ((float4*)sC)[t + i * 256] = ((const float4*)(cayley + (size_t)ij0 * 32))[t + i * 256];
        __syncthreads();
        const int k = t & 31, jc = t >> 5;
        uint_t pk[16];
#pragma unroll
        for (int j2 = 0; j2 < 16; ++j2) {
            pk[j2] = pkbf(sC[(jc * 32 + 2 * j2) * 32 + k], sC[(jc * 32 + 2 * j2 + 1) * 32 + k]);
        }
        uint_t* dst = (uint_t*)(C2t + (size_t)k * 1024 + ij0 + jc * 32);
#pragma unroll
        for (int j2 = 0; j2 < 16; ++j2) dst[j2] = pk[j2];
    }
}

// ---------------------------------------------------------------------------
// Barrier-free MFMA attention, round 11: each wave now processes a FULL
// 64-row q-superblock (4 B-frags qfA..qfD in registers) against its 32-key
// quarter. Per iteration: 5 loads (ka, kb, v0, v1, mask dwordx4) feed
// 20 MFMA + 32 exp -- loads/MFMA 0.6 -> 0.25 (the r10 lever, doubled).
// Grid 512 blocks (2 waves/SIMD; r8 proved occupancy isn't binding).
// __launch_bounds__(256,2) -> 256 VGPR cap, spill impossible (r9 lesson).
// ---------------------------------------------------------------------------
__global__ __launch_bounds__(256, 2) void attn_kernel(
        const uint_t* __restrict__ mb, float* __restrict__ ws) {
    const ushort_t* Qs = (const ushort_t*)(ws + QS16OFF);
    const ushort_t* Ks = (const ushort_t*)(ws + KS16OFF);
    const ushort_t* Vt = (const ushort_t*)(ws + VT16OFF);
    float* Va = ws + VAOFF;
    float* Rv = ws + RVOFF;

    // swizzle (bijective, 512 blocks): bh = ((bid&7)<<1)|bit8, qsb = (bid>>3)&31
    const int bid = blockIdx.x;
    const int bh = ((bid & 7) << 1) | ((bid >> 8) & 1);
    const int qsb = (bid >> 3) & 31;
    const int q0 = qsb * 64;
    const int b = bh >> 3;
    const int t = threadIdx.x;
    const int ks = t >> 6, lane = t & 63;   // wave = key-quarter
    const int quad = lane >> 4, l15 = lane & 15;

    __shared__ float accb[3][4][64][8];   // [ks-1][half][lane][acc0(4)+acc1(4)]
    __shared__ float psL[4][64];

    // Q B-fragments for all four 16-row halves (held all loop)
    const ushort_t* qbase = Qs + ((size_t)(bh * 2048 + q0 + l15)) * 32 + quad * 8;
    const short8 qfA = *(const short8*)(qbase);
    const short8 qfB = *(const short8*)(qbase + 16 * 32);
    const short8 qfC = *(const short8*)(qbase + 32 * 32);
    const short8 qfD = *(const short8*)(qbase + 48 * 32);

    const ushort_t* ka_p = Ks + (size_t)bh * 65536 + (ks * 32 + l15) * 32 + quad * 8;
    const ushort_t* v0_p = Vt + (size_t)bh * 65536 + (size_t)l15 * 2048 + ks * 32 + quad * 8;
    // mask base: [b][qsb][ks][kt][l15][rr]; per-iter stride 64 dwords
    const uint_t* m_p = mb + ((((size_t)(b * 32 + qsb) * 4 + ks) * 16) * 16 + l15) * 4;

    f32x4 accA0 = {0.f,0.f,0.f,0.f}, accA1 = {0.f,0.f,0.f,0.f}, accA2 = {0.f,0.f,0.f,0.f};
    f32x4 accB0 = {0.f,0.f,0.f,0.f}, accB1 = {0.f,0.f,0.f,0.f}, accB2 = {0.f,0.f,0.f,0.f};
    f32x4 accC0 = {0.f,0.f,0.f,0.f}, accC1 = {0.f,0.f,0.f,0.f}, accC2 = {0.f,0.f,0.f,0.f};
    f32x4 accD0 = {0.f,0.f,0.f,0.f}, accD1 = {0.f,0.f,0.f,0.f}, accD2 = {0.f,0.f,0.f,0.f};
    const int bp0 = quad * 4, bp1 = 16 + quad * 4;

    union { uint_t u[4]; short8 s; } ONES;
    {
        const uint_t ov = (l15 == 0) ? 0x3F803F80u : 0u;   // bf16 1.0 pair
        ONES.u[0] = ov; ONES.u[1] = ov; ONES.u[2] = ov; ONES.u[3] = ov;
    }

#pragma unroll 2
    for (int kt = 0; kt < 16; ++kt) {
        const short8 ka = *(const short8*)(ka_p + kt * 4096);
        const short8 kb = *(const short8*)(ka_p + kt * 4096 + 512);
        const short8 v0 = *(const short8*)(v0_p + kt * 128);
        const short8 v1 = *(const short8*)(v0_p + 16 * 2048 + kt * 128);
        const uint4 mw4 = *(const uint4*)(m_p + kt * 64);

        const f32x4 z = {0.f, 0.f, 0.f, 0.f};
        f32x4 sA0 = __builtin_amdgcn_mfma_f32_16x16x32_bf16(ka, qfA, z, 0, 0, 0);
        f32x4 sA1 = __builtin_amdgcn_mfma_f32_16x16x32_bf16(kb, qfA, z, 0, 0, 0);
        f32x4 sB0 = __builtin_amdgcn_mfma_f32_16x16x32_bf16(ka, qfB, z, 0, 0, 0);
        f32x4 sB1 = __builtin_amdgcn_mfma_f32_16x16x32_bf16(kb, qfB, z, 0, 0, 0);
        f32x4 sC0 = __builtin_amdgcn_mfma_f32_16x16x32_bf16(ka, qfC, z, 0, 0, 0);
        f32x4 sC1 = __builtin_amdgcn_mfma_f32_16x16x32_bf16(kb, qfC, z, 0, 0, 0);
        f32x4 sD0 = __builtin_amdgcn_mfma_f32_16x16x32_bf16(ka, qfD, z, 0, 0, 0);
        f32x4 sD1 = __builtin_amdgcn_mfma_f32_16x16x32_bf16(kb, qfD, z, 0, 0, 0);

        {
            float p0[4], p1[4];
#pragma unroll
            for (int r = 0; r < 4; ++r) {
                p0[r] = ((mw4.x >> (bp0 + r)) & 1u) ? exp2f(sA0[r]) : 0.f;
                p1[r] = ((mw4.x >> (bp1 + r)) & 1u) ? exp2f(sA1[r]) : 0.f;
            }
            union { uint_t u[4]; short8 s; } P;
            P.u[0] = pk2(p0[0], p0[1]); P.u[1] = pk2(p0[2], p0[3]);
            P.u[2] = pk2(p1[0], p1[1]); P.u[3] = pk2(p1[2], p1[3]);
            accA0 = __builtin_amdgcn_mfma_f32_16x16x32_bf16(P.s, v0, accA0, 0, 0, 0);
            accA1 = __builtin_amdgcn_mfma_f32_16x16x32_bf16(P.s, v1, accA1, 0, 0, 0);
            accA2 = __builtin_amdgcn_mfma_f32_16x16x32_bf16(P.s, ONES.s, accA2, 0, 0, 0);
        }
        {
            float p0[4], p1[4];
#pragma unroll
            for (int r = 0; r < 4; ++r) {
                p0[r] = ((mw4.y >> (bp0 + r)) & 1u) ? exp2f(sB0[r]) : 0.f;
                p1[r] = ((mw4.y >> (bp1 + r)) & 1u) ? exp2f(sB1[r]) : 0.f;
            }
            union { uint_t u[4]; short8 s; } P;
            P.u[0] = pk2(p0[0], p0[1]); P.u[1] = pk2(p0[2], p0[3]);
            P.u[2] = pk2(p1[0], p1[1]); P.u[3] = pk2(p1[2], p1[3]);
            accB0 = __builtin_amdgcn_mfma_f32_16x16x32_bf16(P.s, v0, accB0, 0, 0, 0);
            accB1 = __builtin_amdgcn_mfma_f32_16x16x32_bf16(P.s, v1, accB1, 0, 0, 0);
            accB2 = __builtin_amdgcn_mfma_f32_16x16x32_bf16(P.s, ONES.s, accB2, 0, 0, 0);
        }
        {
            float p0[4], p1[4];
#pragma unroll
            for (int r = 0; r < 4; ++r) {
                p0[r] = ((mw4.z >> (bp0 + r)) & 1u) ? exp2f(sC0[r]) : 0.f;
                p1[r] = ((mw4.z >> (bp1 + r)) & 1u) ? exp2f(sC1[r]) : 0.f;
            }
            union { uint_t u[4]; short8 s; } P;
            P.u[0] = pk2(p0[0], p0[1]); P.u[1] = pk2(p0[2], p0[3]);
            P.u[2] = pk2(p1[0], p1[1]); P.u[3] = pk2(p1[2], p1[3]);
            accC0 = __builtin_amdgcn_mfma_f32_16x16x32_bf16(P.s, v0, accC0, 0, 0, 0);
            accC1 = __builtin_amdgcn_mfma_f32_16x16x32_bf16(P.s, v1, accC1, 0, 0, 0);
            accC2 = __builtin_amdgcn_mfma_f32_16x16x32_bf16(P.s, ONES.s, accC2, 0, 0, 0);
        }
        {
            float p0[4], p1[4];
#pragma unroll
            for (int r = 0; r < 4; ++r) {
                p0[r] = ((mw4.w >> (bp0 + r)) & 1u) ? exp2f(sD0[r]) : 0.f;
                p1[r] = ((mw4.w >> (bp1 + r)) & 1u) ? exp2f(sD1[r]) : 0.f;
            }
            union { uint_t u[4]; short8 s; } P;
            P.u[0] = pk2(p0[0], p0[1]); P.u[1] = pk2(p0[2], p0[3]);
            P.u[2] = pk2(p1[0], p1[1]); P.u[3] = pk2(p1[2], p1[3]);
            accD0 = __builtin_amdgcn_mfma_f32_16x16x32_bf16(P.s, v0, accD0, 0, 0, 0);
            accD1 = __builtin_amdgcn_mfma_f32_16x16x32_bf16(P.s, v1, accD1, 0, 0, 0);
            accD2 = __builtin_amdgcn_mfma_f32_16x16x32_bf16(P.s, ONES.s, accD2, 0, 0, 0);
        }
    }

    // partial rowsums (col-0 lanes)
    if (l15 == 0) {
#pragma unroll
        for (int r = 0; r < 4; ++r) {
            psL[ks][quad * 4 + r] = accA2[r];
            psL[ks][16 + quad * 4 + r] = accB2[r];
            psL[ks][32 + quad * 4 + r] = accC2[r];
            psL[ks][48 + quad * 4 + r] = accD2[r];
        }
    }
    if (ks != 0) {
#pragma unroll
        for (int i = 0; i < 4; ++i) {
            accb[ks - 1][0][lane][i] = accA0[i];
            accb[ks - 1][0][lane][4 + i] = accA1[i];
            accb[ks - 1][1][lane][i] = accB0[i];
            accb[ks - 1][1][lane][4 + i] = accB1[i];
            accb[ks - 1][2][lane][i] = accC0[i];
            accb[ks - 1][2][lane][4 + i] = accC1[i];
            accb[ks - 1][3][lane][i] = accD0[i];
            accb[ks - 1][3][lane][4 + i] = accD1[i];
        }
    }
    __syncthreads();
    if (ks == 0) {
#pragma unroll
        for (int p = 0; p < 3; ++p) {
#pragma unroll
            for (int i = 0; i < 4; ++i) {
                accA0[i] += accb[p][0][lane][i];
                accA1[i] += accb[p][0][lane][4 + i];
                accB0[i] += accb[p][1][lane][i];
                accB1[i] += accb[p][1][lane][4 + i];
                accC0[i] += accb[p][2][lane][i];
                accC1[i] += accb[p][2][lane][4 + i];
                accD0[i] += accb[p][3][lane][i];
                accD1[i] += accb[p][3][lane][4 + i];
            }
        }
        const f32x4* a0s[4] = {&accA0, &accB0, &accC0, &accD0};
        const f32x4* a1s[4] = {&accA1, &accB1, &accC1, &accD1};
#pragma unroll
        for (int hf = 0; hf < 4; ++hf) {
#pragma unroll
            for (int r = 0; r < 4; ++r) {
                const int row = hf * 16 + quad * 4 + r;
                const float tot = psL[0][row] + psL[1][row] + psL[2][row] + psL[3][row];
                const float inv = (tot > 0.f) ? 1.0f / tot : 0.f;
                const size_t o = ((size_t)(bh * 2048 + q0 + row)) * 32;
                Va[o + l15] = (*a0s[hf])[r] * inv;
                Va[o + 16 + l15] = (*a1s[hf])[r] * inv;
                if ((bh & 7) == 0 && l15 == 0)
                    Rv[(size_t)b * 2048 + q0 + row] = (tot > 0.f) ? 1.0f : 0.f;
            }
        }
    }
}

// ---------------------------------------------------------------------------
// MFMA geometric product + epilogue + Wo (r9/r10-proven).
// ---------------------------------------------------------------------------
__global__ __launch_bounds__(256) void gp_kernel(
        const float* __restrict__ ws, const float* __restrict__ Wo,
        float* __restrict__ out) {
    const float* Va = ws + VAOFF;
    const ushort_t* Qs = (const ushort_t*)(ws + QS16OFF);
    const ushort_t* Kg = (const ushort_t*)(ws + KG16OFF);
    const ushort_t* C2t = (const ushort_t*)(ws + C2TOFF);
    const float* Rv = ws + RVOFF;
    __shared__ ushort_t sC[32 * 1040];
    __shared__ float sH[64 * 32];

    const int t = threadIdx.x;
    const int w = t >> 6, lane = t & 63;
    const int quad = lane >> 4, l15 = lane & 15;

#pragma unroll
    for (int j = 0; j < 16; ++j) {
        const int c = j * 256 + t;
        const int row = c >> 7, col = (c & 127) * 8;
        *(short8*)(&sC[row * 1040 + col]) = *(const short8*)(C2t + row * 1024 + col);
    }

    const int grow0 = blockIdx.x * 64 + w * 16 + l15;
    const int pos = grow0 >> 3, h = grow0 & 7;
    const int b = pos >> 11, l = pos & 2047;
    const size_t gb = ((size_t)((b * 8 + h) * 2048 + l)) * 32;

    float q[32];
#pragma unroll
    for (int j8 = 0; j8 < 4; ++j8) {
        const short8 qv = *(const short8*)(Qs + gb + j8 * 8);
#pragma unroll
        for (int i = 0; i < 8; ++i) q[j8 * 8 + i] = bf2f((ushort_t)qv[i]);
    }
    float u[8];
    {
        const short8 kv = *(const short8*)(Kg + gb + quad * 8);
        const float4 va0 = *(const float4*)(Va + gb + quad * 8);
        const float4 va1 = *(const float4*)(Va + gb + quad * 8 + 4);
        u[0] = va0.x + 0.25f * bf2f((ushort_t)kv[0]);
        u[1] = va0.y + 0.25f * bf2f((ushort_t)kv[1]);
        u[2] = va0.z + 0.25f * bf2f((ushort_t)kv[2]);
        u[3] = va0.w + 0.25f * bf2f((ushort_t)kv[3]);
        u[4] = va1.x + 0.25f * bf2f((ushort_t)kv[4]);
        u[5] = va1.y + 0.25f * bf2f((ushort_t)kv[5]);
        u[6] = va1.z + 0.25f * bf2f((ushort_t)kv[6]);
        u[7] = va1.w + 0.25f * bf2f((ushort_t)kv[7]);
    }
    __syncthreads();

    f32x4 a0 = {0.f, 0.f, 0.f, 0.f};
    f32x4 a1 = {0.f, 0.f, 0.f, 0.f};
    const ushort_t* b0p = sC + (size_t)l15 * 1040 + quad * 8;
    const ushort_t* b1p = sC + (size_t)(16 + l15) * 1040 + quad * 8;

#pragma unroll
    for (int kc = 0; kc < 32; ++kc) {
        const float qk = q[kc];
        union { uint_t u4[4]; short8 s; } F;
        F.u4[0] = pk2(qk * u[0], qk * u[1]);
        F.u4[1] = pk2(qk * u[2], qk * u[3]);
        F.u4[2] = pk2(qk * u[4], qk * u[5]);
        F.u4[3] = pk2(qk * u[6], qk * u[7]);
        const short8 bb0 = *(const short8*)(b0p + kc * 32);
        const short8 bb1 = *(const short8*)(b1p + kc * 32);
        a0 = __builtin_amdgcn_mfma_f32_16x16x32_bf16(F.s, bb0, a0, 0, 0, 0);
        a1 = __builtin_amdgcn_mfma_f32_16x16x32_bf16(F.s, bb1, a1, 0, 0, 0);
    }

    // undo q scale (sqrt(32)) and the folded log2e (x ln2)
    const float SQ32 = 5.656854249492381f * 0.69314718055994531f;
#pragma unroll
    for (int r = 0; r < 4; ++r) {
        const int grow = blockIdx.x * 64 + w * 16 + quad * 4 + r;
        const int pr = grow >> 3, hr = grow & 7;
        const int br = pr >> 11, lr = pr & 2047;
        const size_t vb = ((size_t)((br * 8 + hr) * 2048 + lr)) * 32;
        const float rv = Rv[pr];
        sH[(w * 16 + quad * 4 + r) * 32 + l15] = (a0[r] * SQ32 + Va[vb + l15]) * rv;
        sH[(w * 16 + quad * 4 + r) * 32 + 16 + l15] = (a1[r] * SQ32 + Va[vb + 16 + l15]) * rv;
    }
    __syncthreads();

    const int pp = t >> 5, d2 = t & 31;
    const float* hp = sH + pp * 256;
    const float4* wop = (const float4*)(Wo + (size_t)d2 * 256);
    float o = 0.f;
#pragma unroll 8
    for (int j4 = 0; j4 < 64; ++j4) {
        const float4 wv = wop[j4];
        const float4 hv = *(const float4*)(hp + j4 * 4);
        o += wv.x * hv.x + wv.y * hv.y + wv.z * hv.z + wv.w * hv.w;
    }
    out[((size_t)blockIdx.x * 8 + pp) * 32 + d2] = o;
}

extern "C" void kernel_launch(void* const* d_in, const int* in_sizes, int n_in,
                              void* d_out, int out_size, void* d_ws, size_t ws_size,
                              hipStream_t stream) {
    const float* x      = (const float*)d_in[0];
    const void*  mask   = d_in[1];
    const float* Wq     = (const float*)d_in[2];
    const float* Wk     = (const float*)d_in[3];
    const float* Wv     = (const float*)d_in[4];
    const float* Wo     = (const float*)d_in[5];
    const float* cayley = (const float*)d_in[6];
    const float* gs     = (const float*)d_in[7];
    float* out = (float*)d_out;
    float* ws  = (float*)d_ws;
    uint_t* mb = (uint_t*)(ws + MBOFF);

    prep_kernel<<<dim3(1540), dim3(256), 0, stream>>>(
        (const uint_t*)mask, mb, x, Wq, Wk, Wv, gs, cayley, ws);
    attn_kernel<<<dim3(512), dim3(256), 0, stream>>>(mb, ws);
    gp_kernel<<<dim3(512), dim3(256), 0, stream>>>(ws, Wo, out);
}